// Round 13
// baseline (574.329 us; speedup 1.0000x reference)
//
#include <hip/hip_runtime.h>

typedef unsigned short u16;
typedef unsigned int   u32;

#define EPSBN     1e-5f
#define NEG_SLOPE 0.2f
#define NGRAPH    1024
#define NPB       512         // nodes per bucket (dst >> 9)
#define CHUNK     16384       // edges per chunk (1 << 14); NC <= 512 assumed
#define BKCAP     11264       // LDS pair capacity per bucket == fixed csr stride
#define NTILE     8           // src tiles of 65536 nodes (1MB hrec, fits XCD L2)
#define SLOTS     1536        // staged edges per window (aggregate)

// LESSON (rounds 1-3): LDS f32 atomics ~200cy/wave-op, contention-independent.
// LESSON (round 4): tile coherence must be bucket-level -> sort by (tile, dl).
// LESSON (round 6): scatter live-region x concurrency must fit XCD L2.
// LESSON (round 8): bucket at per-edge-work floor (~60 Gkeys/s).
// LESSON (round 10): verify blocks/CU LDS arithmetic BEFORE growing LDS.
// LESSON (round 12): launch boundaries ~2.4us each (not 10-15); round-9's win
// was removing SERIALIZED tiny kernels. ROUND 13: fold transform-1 into
// k_bucket (rides in latency slack), fold final into jkpool (last-block
// ticket). 10 -> 8 launches, ~12us of exposed work removed.

static __device__ __forceinline__ float bfl(const u16* __restrict__ p, int i){
    return __uint_as_float(((u32)p[i]) << 16);
}
static __device__ __forceinline__ float ldf(const void* __restrict__ p, int i, bool f32){
    return f32 ? ((const float*)p)[i] : bfl((const u16*)p, i);
}
static __device__ __forceinline__ u16 f2bf(float f){
    u32 u = __float_as_uint(f);
    return (u16)((u + 0x7fffu + ((u >> 16) & 1u)) >> 16);
}
static __device__ __forceinline__ void unpack8(uint4 pk, float* a){
    a[0] = __uint_as_float((pk.x & 0xffffu) << 16);
    a[1] = __uint_as_float( pk.x & 0xffff0000u);
    a[2] = __uint_as_float((pk.y & 0xffffu) << 16);
    a[3] = __uint_as_float( pk.y & 0xffff0000u);
    a[4] = __uint_as_float((pk.z & 0xffffu) << 16);
    a[5] = __uint_as_float( pk.z & 0xffff0000u);
    a[6] = __uint_as_float((pk.w & 0xffffu) << 16);
    a[7] = __uint_as_float( pk.w & 0xffff0000u);
}
static __device__ __forceinline__ uint4 pack8(const float* a){
    uint4 pk;
    pk.x = (u32)f2bf(a[0]) | ((u32)f2bf(a[1])<<16);
    pk.y = (u32)f2bf(a[2]) | ((u32)f2bf(a[3])<<16);
    pk.z = (u32)f2bf(a[4]) | ((u32)f2bf(a[5])<<16);
    pk.w = (u32)f2bf(a[6]) | ((u32)f2bf(a[7])<<16);
    return pk;
}

// ---------------- shuffle-based block scan (inclusive), <=16 waves ----------------
static __device__ __forceinline__ int wave_scan_incl(int x){
    int lane = threadIdx.x & 63;
    #pragma unroll
    for (int off = 1; off < 64; off <<= 1){
        int y = __shfl_up(x, off, 64);
        if (lane >= off) x += y;
    }
    return x;
}
static __device__ __forceinline__ int block_scan_incl(int x, int* wpart){
    int t = threadIdx.x, lane = t & 63, wv = t >> 6;
    int nw = blockDim.x >> 6;
    int ws = wave_scan_incl(x);
    __syncthreads();                 // protect wpart reuse across scans
    if (lane == 63) wpart[wv] = ws;
    __syncthreads();
    if (wv == 0){
        int p = (lane < nw) ? wpart[lane] : 0;
        p = wave_scan_incl(p);
        if (lane < nw) wpart[lane] = p;
    }
    __syncthreads();
    int base = wv ? wpart[wv-1] : 0;
    return base + ws;
}

// ================= atomic-free radix CSR build (LDS-staged chunk sort) =================
// Block 0 also: dtype sniff -> dflag[0], ticket dflag[1]=0, zero stats1/2/3.
__global__ __launch_bounds__(1024) void k_binsort(const int* __restrict__ src,
                                                  const int* __restrict__ dst,
                                                  u32* __restrict__ stage,
                                                  int* __restrict__ matL,
                                                  int E, int B,
                                                  const u16* __restrict__ x16,
                                                  int* __restrict__ dflag,
                                                  float* __restrict__ statsAll){
    __shared__ u32 pr[CHUNK];        // 64KB: sorted pairs
    __shared__ int h[2048];          // 8KB
    __shared__ int wpart[16];
    int c = blockIdx.x, t = threadIdx.x;
    if (c == 0){
        if (t < 64){
            bool hit = false;
            for (int i = t; i < 128; i += 64){
                float v = bfl(x16, i);
                if (!(fabsf(v) <= 1e6f)) hit = true;
            }
            unsigned long long m = __ballot(hit);
            if (t == 0){ dflag[0] = (m != 0ull) ? 1 : 0; dflag[1] = 0; }
        }
        if (t >= 64 && t < 112) statsAll[t - 64] = 0.f;
    }
    int e0 = c << 14, e1 = min(e0 + CHUNK, E), cn = e1 - e0;
    for (int b = t; b < B; b += 1024) h[b] = 0;
    __syncthreads();
    for (int i = e0 + t; i < e1; i += 1024) atomicAdd(&h[dst[i] >> 9], 1);
    __syncthreads();
    int base = t << 1, run = 0, loc[2];     // per = 2 (B <= 2048)
    #pragma unroll
    for (int j = 0; j < 2; j++){
        int b = base + j;
        int v = (b < B) ? h[b] : 0;
        loc[j] = run; run += v;
    }
    int incl = block_scan_incl(run, wpart);
    int bex = incl - run;
    __syncthreads();
    #pragma unroll
    for (int j = 0; j < 2; j++){
        int b = base + j;
        if (b < B) h[b] = bex + loc[j];
    }
    __syncthreads();
    int* mrow = matL + (size_t)c * (B+1);
    for (int b = t; b < B; b += 1024) mrow[b] = h[b];
    if (t == 0) mrow[B] = cn;
    __syncthreads();
    for (int i = e0 + t; i < e1; i += 1024){
        int d = dst[i];
        int b = d >> 9;
        int p = atomicAdd(&h[b], 1);
        pr[p] = ((u32)src[i] << 9) | (u32)(d & 511);
    }
    __syncthreads();
    u32* srow = stage + ((size_t)c << 14);
    for (int i = t; i < cn; i += 1024) srow[i] = pr[i];
}

// per-bucket single-pass counting sort by (srcTile<<9)|dl, LDS-staged pr.
// 1024 threads = 16 waves x 2 blocks/CU; shuffle scans; matL read strided;
// csr base = k*BKCAP. ALSO performs layer-1 transform for its node range
// (x @ W1, hd = h.ad1) — rides in the sort's latency slack.
__global__ __launch_bounds__(1024) void k_bucket(const u32* __restrict__ stage,
                                                 const int* __restrict__ matL,
                                                 int* __restrict__ tileOfs,
                                                 u32* __restrict__ csr,
                                                 int N, int B, int NC,
                                                 const void* __restrict__ x,
                                                 const void* __restrict__ W1,
                                                 const void* __restrict__ ad1,
                                                 const int* __restrict__ dflag,
                                                 uint4* __restrict__ hrec,
                                                 float* __restrict__ hd){
    __shared__ u32 pr[BKCAP];        // 44KB
    __shared__ int hist[4096];       // 16KB: (tile<<9)|dl
    __shared__ int sc[1024];         // 4KB: searchable chunk-prefix
    __shared__ int lofsA[512];       // 2KB
    __shared__ int wpart[16];
    __shared__ float WlT[64], adT[8];
    int k = blockIdx.x, t = threadIdx.x;
    int n0 = k << 9, n1 = min(n0 + NPB, N), nn = n1 - n0;
    const bool f32 = dflag[0] != 0;
    int cnt = 0, lofs = 0;
    if (t < NC){
        lofs = matL[(size_t)t*(B+1) + k];
        cnt  = matL[(size_t)t*(B+1) + k + 1] - lofs;
    }
    if (t < 512) lofsA[t] = lofs;
    if (t >= 512 && t < 576) WlT[t-512] = ((t-512) < 56) ? ldf(W1, t-512, f32) : 0.f;
    if (t >= 576 && t < 584) adT[t-576] = ldf(ad1, t-576, f32);
    int incl1 = block_scan_incl(cnt, wpart);
    sc[t] = incl1;
    __syncthreads();
    int total = sc[1023];
    int ec    = min(total, BKCAP - nn);
    for (int pidx = t; pidx < ec; pidx += 1024){
        int lo = 0, hi = 511;
        while (lo < hi){ int mid = (lo + hi) >> 1; if (sc[mid] > pidx) hi = mid; else lo = mid + 1; }
        int segStart = lo ? sc[lo-1] : 0;
        pr[pidx] = stage[((size_t)lo << 14) + lofsA[lo] + (pidx - segStart)];
    }
    __syncthreads();
    for (int j = t; j < nn; j += 1024) pr[ec + j] = ((u32)(n0 + j) << 9) | (u32)j;  // self-loops
    int ecnt = ec + nn;
    for (int i = t; i < 4096; i += 1024) hist[i] = 0;
    __syncthreads();
    for (int i = t; i < ecnt; i += 1024){
        u32 pk = pr[i];
        int dl = pk & 511;
        int tile = min((int)(pk >> 9) >> 16, NTILE-1);
        atomicAdd(&hist[(tile << 9) + dl], 1);
    }
    __syncthreads();
    int base = t << 2, run = 0, loc[4];
    #pragma unroll
    for (int j = 0; j < 4; j++){ loc[j] = run; run += hist[base + j]; }
    int incl2 = block_scan_incl(run, wpart);
    int bex = incl2 - run;          // exclusive bin-group base
    __syncthreads();
    #pragma unroll
    for (int j = 0; j < 4; j++) hist[base + j] = bex + loc[j];
    // tile ti starts at bin ti*512 -> thread ti*128 (4 bins/thread), local bin 0
    if ((t & 127) == 0) tileOfs[(size_t)k*9 + (t >> 7)] = bex;
    if (t == 0)         tileOfs[(size_t)k*9 + 8] = ecnt;
    __syncthreads();
    size_t wbase = (size_t)k * BKCAP;
    for (int i = t; i < ecnt; i += 1024){
        u32 pk = pr[i];
        int dl = pk & 511;
        int tile = min((int)(pk >> 9) >> 16, NTILE-1);
        int p = atomicAdd(&hist[(tile << 9) + dl], 1);
        csr[wbase + p] = pk;
    }
    // ---- fused layer-1 transform for this block's node range ----
    if (t < nn){
        int i = n0 + t;
        float a[8];
        #pragma unroll
        for (int kk = 0; kk < 7; kk++) a[kk] = ldf(x, i*7 + kk, f32);
        a[7] = 0.f;
        float h[8];
        #pragma unroll
        for (int j = 0; j < 8; j++){
            float acc = 0.f;
            #pragma unroll
            for (int kk = 0; kk < 8; kk++) acc += a[kk]*WlT[kk*8+j];
            h[j] = acc;
        }
        float s2 = 0.f;
        #pragma unroll
        for (int j = 0; j < 8; j++) s2 += h[j]*adT[j];
        hd[i] = s2;
        hrec[i] = pack8(h);
    }
}

// ---------------- node transform (+ fused BN/PReLU of previous layer) ----------------
__global__ void k_transform(const uint4* __restrict__ actpk, const void* __restrict__ xraw,
                            const int* __restrict__ dflag, int fin,
                            const void* __restrict__ W, const void* __restrict__ adst,
                            const float* __restrict__ stats, const void* __restrict__ gamma,
                            const void* __restrict__ beta, const void* __restrict__ alpha,
                            uint4* __restrict__ hrec, float* __restrict__ hd, int n){
    const bool f32 = dflag[0] != 0;
    __shared__ float Wl[64], dl[8], scl[8], sft[8], alv;
    int t = threadIdx.x;
    if (t < 64)            Wl[t]   = (t < fin*8) ? ldf(W, t, f32) : 0.f;
    if (t >= 64 && t < 72) dl[t-64] = ldf(adst, t-64, f32);
    if (t == 80) alv = ldf(alpha, 0, f32);
    if (stats && t < 8){
        float invN = 1.f/(float)n;
        float mu  = stats[t]*invN;
        float var = fmaxf(stats[8+t]*invN - mu*mu, 0.f);
        float s   = ldf(gamma, t, f32)*rsqrtf(var + EPSBN);
        scl[t] = s; sft[t] = ldf(beta, t, f32) - mu*s;
    }
    __syncthreads();
    int i = blockIdx.x*blockDim.x + t;
    if (i >= n) return;
    float a[8];
    if (xraw){
        #pragma unroll
        for (int k=0;k<7;k++) a[k] = ldf(xraw, i*7 + k, f32);
        a[7] = 0.f;
    } else {
        unpack8(actpk[i], a);
        #pragma unroll
        for (int j=0;j<8;j++){
            float y = a[j]*scl[j] + sft[j];
            a[j] = (y > 0.f) ? y : alv*y;
        }
    }
    float h[8];
    #pragma unroll
    for (int j=0;j<8;j++){
        float acc = 0.f;
        #pragma unroll
        for (int k=0;k<8;k++) acc += a[k]*Wl[k*8+j];
        h[j] = acc;
    }
    float s2 = 0.f;
    #pragma unroll
    for (int j=0;j<8;j++) s2 += h[j]*dl[j];
    hd[i] = s2;
    hrec[i] = pack8(h);
}

// ---------------- GAT aggregate: tile-major, scalar-chain-in-A, zero-atomic ----------
__global__ __launch_bounds__(512) void k_aggregate(
        const u32* __restrict__ csr,
        const int* __restrict__ tileOfs,
        const uint4* __restrict__ hrec, const float* __restrict__ hd,
        const void* __restrict__ asrc, const int* __restrict__ dflag,
        uint4* __restrict__ act, float* __restrict__ stats, int n){
    const bool f32 = dflag[0] != 0;
    __shared__ u32   stg[4*SLOTS];   // 24KB: hv.x,y,z,w planes (bf16-packed)
    __shared__ float swp[SLOTS];     // 6KB: w plane
    __shared__ u16   sdl[SLOTS];     // 3KB: dl plane
    __shared__ float hdl[512];       // 2KB
    __shared__ u16 bs[512], be[512]; // 2KB run bounds per row
    __shared__ float alS[8];
    __shared__ float sred[8][16];
    __shared__ int tofS[9];
    int k = blockIdx.x, t = threadIdx.x;
    int n0 = k << 9;
    int nn = min(NPB, n - n0);
    if (t < 8) alS[t] = ldf(asrc, t, f32);
    if (t < 9) tofS[t] = tileOfs[(size_t)k*9 + t];
    hdl[t] = (t < nn) ? hd[n0 + t] : 0.f;
    const u32* ecsr = csr + (size_t)k * BKCAP;   // fixed-stride bucket base
    __syncthreads();
    float al[8];
    #pragma unroll
    for (int j = 0; j < 8; j++) al[j] = alS[j];
    float acc[8] = {0,0,0,0,0,0,0,0};
    float den = 0.f;

    // ---- flattened window walk: (wt, wc) -> first valid window ----
    int wt = 0, wc = 0;
    while (wt < NTILE && wc >= tofS[wt+1]){ wt++; if (wt < NTILE) wc = tofS[wt]; }

    u32 pkc[3]; uint4 hvc[3];
    if (wt < NTILE){
        int L = min(SLOTS, tofS[wt+1] - wc);
        #pragma unroll
        for (int j = 0; j < 3; j++) pkc[j] = ecsr[wc + min(t + (j << 9), L - 1)];
        #pragma unroll
        for (int j = 0; j < 3; j++) hvc[j] = hrec[pkc[j] >> 9];
    }

    while (wt < NTILE){
        int L = min(SLOTS, tofS[wt+1] - wc);
        __syncthreads();             // stg/swp/sdl/bs/be free (prev phase B done)
        // ---- phase A: stage hv + compute scalar chain (uniform) ----
        #pragma unroll
        for (int j = 0; j < 3; j++){
            int i = t + (j << 9);
            float h[8]; unpack8(hvc[j], h);
            int dl = (int)(pkc[j] & 511u);
            float e = hdl[dl];
            #pragma unroll
            for (int q = 0; q < 8; q++) e += h[q]*al[q];
            e = (e > 0.f) ? e : NEG_SLOPE*e;
            float w = __expf(e);
            if (i < L){
                stg[0*SLOTS + i] = hvc[j].x;
                stg[1*SLOTS + i] = hvc[j].y;
                stg[2*SLOTS + i] = hvc[j].z;
                stg[3*SLOTS + i] = hvc[j].w;
                swp[i] = w;
                sdl[i] = (u16)dl;
            }
        }
        bs[t] = 0; be[t] = 0;
        __syncthreads();             // stg + clears visible
        // ---- next window coords + register prefetch (hidden under detect+B) ----
        int nwt = wt, nwc = wc + SLOTS;
        while (nwt < NTILE && nwc >= tofS[nwt+1]){ nwt++; if (nwt < NTILE) nwc = tofS[nwt]; }
        if (nwt < NTILE){
            int Ln = min(SLOTS, tofS[nwt+1] - nwc);
            #pragma unroll
            for (int j = 0; j < 3; j++) pkc[j] = ecsr[nwc + min(t + (j << 9), Ln - 1)];
            #pragma unroll
            for (int j = 0; j < 3; j++) hvc[j] = hrec[pkc[j] >> 9];
        }
        // ---- boundary detect: dl sorted in window -> one run per row ----
        for (int i = t; i < L; i += 512){
            int dl = (int)sdl[i];
            if (i == 0){
                bs[dl] = 0;
            } else {
                int dp = (int)sdl[i - 1];
                if (dp != dl){ bs[dl] = (u16)i; be[dp] = (u16)i; }
            }
            if (i == L-1) be[dl] = (u16)L;
        }
        __syncthreads();             // bs/be ready
        // ---- phase B: row-owner weighted sum (unpack + FMA only) ----
        {
            int p0 = bs[t], p1 = be[t];
            for (int p = p0; p < p1; ++p){
                uint4 hv = make_uint4(stg[0*SLOTS + p], stg[1*SLOTS + p],
                                      stg[2*SLOTS + p], stg[3*SLOTS + p]);
                float h[8]; unpack8(hv, h);
                float w = swp[p];
                den += w;
                #pragma unroll
                for (int q = 0; q < 8; q++) acc[q] += w*h[q];
            }
        }
        wt = nwt; wc = nwc;
    }

    float o[8] = {0,0,0,0,0,0,0,0};
    if (t < nn){
        float inv = 1.f/(den + 1e-16f);
        #pragma unroll
        for (int j = 0; j < 8; j++) o[j] = acc[j]*inv;
        act[n0 + t] = pack8(o);
    }
    // BN stats partials (sum, sumsq per channel) -> global atomics
    float v[16];
    #pragma unroll
    for (int j=0;j<8;j++){ v[j]=o[j]; v[8+j]=o[j]*o[j]; }
    #pragma unroll
    for (int off=32; off>0; off>>=1){
        #pragma unroll
        for (int j=0;j<16;j++) v[j] += __shfl_down(v[j], off, 64);
    }
    int lane = t & 63, wv = t >> 6;
    if (lane == 0){
        #pragma unroll
        for (int j=0;j<16;j++) sred[wv][j] = v[j];
    }
    __syncthreads();
    if (t < 16){
        float tot = 0.f;
        #pragma unroll
        for (int w=0; w<8; w++) tot += sred[w][t];
        atomicAdd(&stats[t], tot);
    }
}

// ---------------- JK-cat (BN+PReLU fused) @ Wjk + bjk, pooled per graph,
//                  + last-block MLP head (device-scope ticket) ----------------
static __device__ __forceinline__ int lowerb(const int* __restrict__ a, int n, int key){
    int lo = 0, hi = n;
    while (lo < hi){ int mid = (lo + hi) >> 1; if (a[mid] < key) lo = mid + 1; else hi = mid; }
    return lo;
}

__global__ __launch_bounds__(256) void k_jkpool(
        const uint4* __restrict__ a1, const uint4* __restrict__ a2, const uint4* __restrict__ a3,
        const float* __restrict__ st1, const float* __restrict__ st2, const float* __restrict__ st3,
        const void* __restrict__ g1, const void* __restrict__ be1,
        const void* __restrict__ g2, const void* __restrict__ be2,
        const void* __restrict__ g3, const void* __restrict__ be3,
        const void* __restrict__ alpha,
        const void* __restrict__ Wjk, const void* __restrict__ bjk,
        const int* __restrict__ dflag,
        const int* __restrict__ batch, float* __restrict__ pooled, int n,
        int* __restrict__ ticket,
        const void* __restrict__ Wm1, const void* __restrict__ bm1,
        const void* __restrict__ gm, const void* __restrict__ bem,
        const void* __restrict__ am,
        const void* __restrict__ Wm2, const void* __restrict__ bm2,
        float* __restrict__ out, int G){
    const bool f32 = dflag[0] != 0;
    __shared__ float Wl[192], bl[8], scl[24], sft[24], alv;
    __shared__ int rng[2];
    int t = threadIdx.x, g = blockIdx.x;
    if (t < 192) Wl[t] = ldf(Wjk, t, f32);
    if (t < 8)   bl[t] = ldf(bjk, t, f32);
    if (t < 24){
        int L = t >> 3, j = t & 7;
        const float* st = (L==0)? st1 : (L==1)? st2 : st3;
        const void* gg  = (L==0)? g1  : (L==1)? g2  : g3;
        const void* bb_ = (L==0)? be1 : (L==1)? be2 : be3;
        float invN = 1.f/(float)n;
        float mu  = st[j]*invN;
        float var = fmaxf(st[8+j]*invN - mu*mu, 0.f);
        float s   = ldf(gg, j, f32)*rsqrtf(var + EPSBN);
        scl[t] = s; sft[t] = ldf(bb_, j, f32) - mu*s;
    }
    if (t == 30) alv = ldf(alpha, 0, f32);
    if (t == 0) rng[0] = lowerb(batch, n, g);
    if (t == 1) rng[1] = lowerb(batch, n, g+1);
    __syncthreads();
    int lo = rng[0], hi = rng[1];
    float pa[8] = {0,0,0,0,0,0,0,0};
    for (int i = lo + t; i < hi; i += 256){
        float c[24];
        unpack8(a1[i], c);
        unpack8(a2[i], c+8);
        unpack8(a3[i], c+16);
        #pragma unroll
        for (int k=0;k<24;k++){
            float y = c[k]*scl[k] + sft[k];
            c[k] = (y > 0.f) ? y : alv*y;
        }
        #pragma unroll
        for (int j=0;j<8;j++){
            float acc = bl[j];
            #pragma unroll
            for (int k=0;k<24;k++) acc += c[k]*Wl[k*8+j];
            pa[j] += acc;
        }
    }
    #pragma unroll
    for (int off=32; off>0; off>>=1){
        #pragma unroll
        for (int j=0;j<8;j++) pa[j] += __shfl_down(pa[j], off, 64);
    }
    __shared__ float sr[4][8];
    int lane = t & 63, wv = t >> 6;
    if (lane == 0){
        #pragma unroll
        for (int j=0;j<8;j++) sr[wv][j] = pa[j];
    }
    __syncthreads();
    if (t < 8){
        float tot = sr[0][t]+sr[1][t]+sr[2][t]+sr[3][t];
        pooled[(size_t)g*8 + t] = tot;
    }
    // ---- last-block runs the MLP head ----
    __threadfence();
    __shared__ int isLast;
    if (t == 0){
        int my = atomicAdd(ticket, 1);
        isLast = (my == (int)gridDim.x - 1) ? 1 : 0;
    }
    __syncthreads();
    if (!isLast) return;
    __threadfence();                 // acquire: all pooled writes visible
    // 256 threads, 4 graphs each (G <= 1024)
    float tv[4][8];
    float v[16];
    #pragma unroll
    for (int j=0;j<16;j++) v[j] = 0.f;
    #pragma unroll
    for (int gg=0; gg<4; gg++){
        int g2 = t + (gg << 8);
        #pragma unroll
        for (int j=0;j<8;j++) tv[gg][j] = 0.f;
        if (g2 < G){
            float r[8];
            #pragma unroll
            for (int j=0;j<8;j++) r[j] = pooled[(size_t)g2*8+j];
            #pragma unroll
            for (int j=0;j<8;j++){
                float acc = ldf(bm1, j, f32);
                #pragma unroll
                for (int kk=0;kk<8;kk++) acc += r[kk]*ldf(Wm1, kk*8+j, f32);
                tv[gg][j] = acc;
                v[j]   += acc;
                v[8+j] += acc*acc;
            }
        }
    }
    #pragma unroll
    for (int off=32; off>0; off>>=1){
        #pragma unroll
        for (int j=0;j<16;j++) v[j] += __shfl_down(v[j], off, 64);
    }
    __shared__ float sfin[4][16];
    if (lane == 0){
        #pragma unroll
        for (int j=0;j<16;j++) sfin[wv][j] = v[j];
    }
    __syncthreads();
    __shared__ float stt[16];
    if (t < 16){
        float tot = sfin[0][t]+sfin[1][t]+sfin[2][t]+sfin[3][t];
        stt[t] = tot;
    }
    __syncthreads();
    float a = ldf(am, 0, f32);
    float invG = 1.f/(float)G;
    #pragma unroll
    for (int gg=0; gg<4; gg++){
        int g2 = t + (gg << 8);
        if (g2 < G){
            float m1[8];
            #pragma unroll
            for (int j=0;j<8;j++){
                float mu  = stt[j]*invG;
                float var = fmaxf(stt[8+j]*invG - mu*mu, 0.f);
                float y = (tv[gg][j]-mu)*rsqrtf(var+EPSBN)*ldf(gm,j,f32)+ldf(bem,j,f32);
                m1[j] = (y>0.f)? y : a*y;
            }
            #pragma unroll
            for (int c=0;c<2;c++){
                float oacc = ldf(bm2, c, f32);
                #pragma unroll
                for (int kk=0;kk<8;kk++) oacc += m1[kk]*ldf(Wm2, kk*2+c, f32);
                out[(size_t)g2*2+c] = oacc;
            }
        }
    }
}

extern "C" void kernel_launch(void* const* d_in, const int* in_sizes, int n_in,
                              void* d_out, int out_size, void* d_ws, size_t ws_size,
                              hipStream_t stream){
    const u16* x16   = (const u16*)d_in[0];
    const void* x    = d_in[0];
    const int* ei    = (const int*)d_in[1];
    const int* batch = (const int*)d_in[2];
    int N = in_sizes[2];
    int E = in_sizes[1] / 2;
    const int* srcA = ei;
    const int* dstA = ei + E;
    const void *W1=d_in[3],  *as1=d_in[4],  *ad1=d_in[5];
    const void *W2=d_in[7],  *as2=d_in[8],  *ad2=d_in[9];
    const void *W3=d_in[11], *as3=d_in[12], *ad3=d_in[13];
    const void *g1=d_in[15], *be1=d_in[16];
    const void *g2=d_in[17], *be2=d_in[18];
    const void *g3=d_in[19], *be3=d_in[20];
    const void *agnn=d_in[21];
    const void *Wjk=d_in[22], *bjk=d_in[23];
    const void *Wm1=d_in[24], *bm1=d_in[25];
    const void *gm =d_in[26], *bem=d_in[27];
    const void *amlp=d_in[28];
    const void *Wm2=d_in[29], *bm2=d_in[30];

    char* p = (char*)d_ws;
    auto carve = [&](size_t bytes) -> void* {
        void* r = (void*)p;
        p += (bytes + 255) & ~(size_t)255;
        return r;
    };
    int nb512 = (N + 511)/512;
    int B  = (N + NPB - 1) / NPB;
    int NC = (E + CHUNK - 1) / CHUNK;          // <= 512
    int*   dflag  = (int*)  carve(256);        // [0]=f32 flag, [1]=jkpool ticket
    int*   tileOfs= (int*)  carve((size_t)B*9*4);
    int*   matL   = (int*)  carve((size_t)NC*(B+1)*4);
    u32*   stage  = (u32*)  carve((size_t)NC*CHUNK*4);
    u32*   csr    = (u32*)  carve((size_t)B*BKCAP*4);   // fixed-stride buckets
    uint4* hrec   = (uint4*)carve((size_t)N*16);
    float* hd     = (float*)carve((size_t)N*4);
    uint4* act1   = (uint4*)carve((size_t)N*16);
    uint4* act2   = (uint4*)carve((size_t)N*16);
    uint4* act3   = (uint4*)carve((size_t)N*16);
    float* statsA = (float*)carve(256);        // 48 floats: stats1|stats2|stats3
    float* stats1 = statsA;
    float* stats2 = statsA + 16;
    float* stats3 = statsA + 32;
    float* pooled = (float*)carve((size_t)NGRAPH*32);
    (void)ws_size; (void)n_in;

    // ---- CSR build (+ sniff/stats/ticket init, + fused layer-1 transform) ----
    k_binsort <<<NC, 1024, 0, stream>>>(srcA, dstA, stage, matL, E, B, x16, dflag, statsA);
    k_bucket  <<<B, 1024, 0, stream>>>(stage, matL, tileOfs, csr, N, B, NC,
                                       x, W1, ad1, dflag, hrec, hd);

    // layer 1 aggregate (transform-1 already done in k_bucket)
    k_aggregate <<<B, 512, 0, stream>>>(csr, tileOfs, hrec, hd, as1, dflag, act1, stats1, N);
    // layer 2 (BN1+PReLU fused into transform)
    k_transform <<<nb512, 512, 0, stream>>>(act1, nullptr, dflag, 8, W2, ad2,
                                            stats1, g1, be1, agnn, hrec, hd, N);
    k_aggregate <<<B, 512, 0, stream>>>(csr, tileOfs, hrec, hd, as2, dflag, act2, stats2, N);
    // layer 3
    k_transform <<<nb512, 512, 0, stream>>>(act2, nullptr, dflag, 8, W3, ad3,
                                            stats2, g2, be2, agnn, hrec, hd, N);
    k_aggregate <<<B, 512, 0, stream>>>(csr, tileOfs, hrec, hd, as3, dflag, act3, stats3, N);

    // JK (BN+PReLU fused) + pool + last-block MLP head
    int G = out_size / 2;
    k_jkpool<<<NGRAPH, 256, 0, stream>>>(act1, act2, act3, stats1, stats2, stats3,
                                         g1, be1, g2, be2, g3, be3, agnn,
                                         Wjk, bjk, dflag, batch, pooled, N,
                                         dflag + 1, Wm1, bm1, gm, bem, amlp, Wm2, bm2,
                                         (float*)d_out, G);
}

// Round 14
// 510.722 us; speedup vs baseline: 1.1245x; 1.1245x over previous
//
#include <hip/hip_runtime.h>

typedef unsigned short u16;
typedef unsigned int   u32;

#define EPSBN     1e-5f
#define NEG_SLOPE 0.2f
#define NGRAPH    1024
#define NPB       512         // nodes per bucket (dst >> 9)
#define CHUNK     16384       // edges per chunk (1 << 14); NC <= 512 assumed
#define BKCAP     11264       // LDS pair capacity per bucket == fixed csr stride
#define NTILE     8           // src tiles of 65536 nodes (1MB hrec, fits XCD L2)
#define SLOTS     1536        // staged edges per window (aggregate)

// LESSON (rounds 1-3): LDS f32 atomics ~200cy/wave-op, contention-independent.
// LESSON (round 4): tile coherence must be bucket-level -> sort by (tile, dl).
// LESSON (round 6): scatter live-region x concurrency must fit XCD L2.
// LESSON (round 8): bucket at per-edge-work floor (~60 Gkeys/s).
// LESSON (round 10): verify blocks/CU LDS arithmetic BEFORE growing LDS.
// LESSON (round 12): launch boundaries ~2.4us each; only SERIALIZED tiny
// kernels between big ones are expensive.
// LESSON (round 13): fusing cold tail code (MLP head) into a hot streaming
// kernel (jkpool) inflated VGPR 64->156, occupancy 40->8.8%, 14->138us.
// Never fuse register-heavy cold code into a hot path. ROUND 14: revert
// jkpool head fusion (standalone k_final); keep bucket+transform1 fusion.

static __device__ __forceinline__ float bfl(const u16* __restrict__ p, int i){
    return __uint_as_float(((u32)p[i]) << 16);
}
static __device__ __forceinline__ float ldf(const void* __restrict__ p, int i, bool f32){
    return f32 ? ((const float*)p)[i] : bfl((const u16*)p, i);
}
static __device__ __forceinline__ u16 f2bf(float f){
    u32 u = __float_as_uint(f);
    return (u16)((u + 0x7fffu + ((u >> 16) & 1u)) >> 16);
}
static __device__ __forceinline__ void unpack8(uint4 pk, float* a){
    a[0] = __uint_as_float((pk.x & 0xffffu) << 16);
    a[1] = __uint_as_float( pk.x & 0xffff0000u);
    a[2] = __uint_as_float((pk.y & 0xffffu) << 16);
    a[3] = __uint_as_float( pk.y & 0xffff0000u);
    a[4] = __uint_as_float((pk.z & 0xffffu) << 16);
    a[5] = __uint_as_float( pk.z & 0xffff0000u);
    a[6] = __uint_as_float((pk.w & 0xffffu) << 16);
    a[7] = __uint_as_float( pk.w & 0xffff0000u);
}
static __device__ __forceinline__ uint4 pack8(const float* a){
    uint4 pk;
    pk.x = (u32)f2bf(a[0]) | ((u32)f2bf(a[1])<<16);
    pk.y = (u32)f2bf(a[2]) | ((u32)f2bf(a[3])<<16);
    pk.z = (u32)f2bf(a[4]) | ((u32)f2bf(a[5])<<16);
    pk.w = (u32)f2bf(a[6]) | ((u32)f2bf(a[7])<<16);
    return pk;
}

// ---------------- shuffle-based block scan (inclusive), <=16 waves ----------------
static __device__ __forceinline__ int wave_scan_incl(int x){
    int lane = threadIdx.x & 63;
    #pragma unroll
    for (int off = 1; off < 64; off <<= 1){
        int y = __shfl_up(x, off, 64);
        if (lane >= off) x += y;
    }
    return x;
}
static __device__ __forceinline__ int block_scan_incl(int x, int* wpart){
    int t = threadIdx.x, lane = t & 63, wv = t >> 6;
    int nw = blockDim.x >> 6;
    int ws = wave_scan_incl(x);
    __syncthreads();                 // protect wpart reuse across scans
    if (lane == 63) wpart[wv] = ws;
    __syncthreads();
    if (wv == 0){
        int p = (lane < nw) ? wpart[lane] : 0;
        p = wave_scan_incl(p);
        if (lane < nw) wpart[lane] = p;
    }
    __syncthreads();
    int base = wv ? wpart[wv-1] : 0;
    return base + ws;
}

// ================= atomic-free radix CSR build (LDS-staged chunk sort) =================
// Block 0 also: dtype sniff -> dflag[0], zero stats1/2/3.
__global__ __launch_bounds__(1024) void k_binsort(const int* __restrict__ src,
                                                  const int* __restrict__ dst,
                                                  u32* __restrict__ stage,
                                                  int* __restrict__ matL,
                                                  int E, int B,
                                                  const u16* __restrict__ x16,
                                                  int* __restrict__ dflag,
                                                  float* __restrict__ statsAll){
    __shared__ u32 pr[CHUNK];        // 64KB: sorted pairs
    __shared__ int h[2048];          // 8KB
    __shared__ int wpart[16];
    int c = blockIdx.x, t = threadIdx.x;
    if (c == 0){
        if (t < 64){
            bool hit = false;
            for (int i = t; i < 128; i += 64){
                float v = bfl(x16, i);
                if (!(fabsf(v) <= 1e6f)) hit = true;
            }
            unsigned long long m = __ballot(hit);
            if (t == 0) dflag[0] = (m != 0ull) ? 1 : 0;
        }
        if (t >= 64 && t < 112) statsAll[t - 64] = 0.f;
    }
    int e0 = c << 14, e1 = min(e0 + CHUNK, E), cn = e1 - e0;
    for (int b = t; b < B; b += 1024) h[b] = 0;
    __syncthreads();
    for (int i = e0 + t; i < e1; i += 1024) atomicAdd(&h[dst[i] >> 9], 1);
    __syncthreads();
    int base = t << 1, run = 0, loc[2];     // per = 2 (B <= 2048)
    #pragma unroll
    for (int j = 0; j < 2; j++){
        int b = base + j;
        int v = (b < B) ? h[b] : 0;
        loc[j] = run; run += v;
    }
    int incl = block_scan_incl(run, wpart);
    int bex = incl - run;
    __syncthreads();
    #pragma unroll
    for (int j = 0; j < 2; j++){
        int b = base + j;
        if (b < B) h[b] = bex + loc[j];
    }
    __syncthreads();
    int* mrow = matL + (size_t)c * (B+1);
    for (int b = t; b < B; b += 1024) mrow[b] = h[b];
    if (t == 0) mrow[B] = cn;
    __syncthreads();
    for (int i = e0 + t; i < e1; i += 1024){
        int d = dst[i];
        int b = d >> 9;
        int p = atomicAdd(&h[b], 1);
        pr[p] = ((u32)src[i] << 9) | (u32)(d & 511);
    }
    __syncthreads();
    u32* srow = stage + ((size_t)c << 14);
    for (int i = t; i < cn; i += 1024) srow[i] = pr[i];
}

// per-bucket single-pass counting sort by (srcTile<<9)|dl, LDS-staged pr.
// 1024 threads = 16 waves x 2 blocks/CU; shuffle scans; matL read strided;
// csr base = k*BKCAP. ALSO performs layer-1 transform for its node range
// (x @ W1, hd = h.ad1) — rides in the sort's latency slack.
__global__ __launch_bounds__(1024) void k_bucket(const u32* __restrict__ stage,
                                                 const int* __restrict__ matL,
                                                 int* __restrict__ tileOfs,
                                                 u32* __restrict__ csr,
                                                 int N, int B, int NC,
                                                 const void* __restrict__ x,
                                                 const void* __restrict__ W1,
                                                 const void* __restrict__ ad1,
                                                 const int* __restrict__ dflag,
                                                 uint4* __restrict__ hrec,
                                                 float* __restrict__ hd){
    __shared__ u32 pr[BKCAP];        // 44KB
    __shared__ int hist[4096];       // 16KB: (tile<<9)|dl
    __shared__ int sc[1024];         // 4KB: searchable chunk-prefix
    __shared__ int lofsA[512];       // 2KB
    __shared__ int wpart[16];
    __shared__ float WlT[64], adT[8];
    int k = blockIdx.x, t = threadIdx.x;
    int n0 = k << 9, n1 = min(n0 + NPB, N), nn = n1 - n0;
    const bool f32 = dflag[0] != 0;
    int cnt = 0, lofs = 0;
    if (t < NC){
        lofs = matL[(size_t)t*(B+1) + k];
        cnt  = matL[(size_t)t*(B+1) + k + 1] - lofs;
    }
    if (t < 512) lofsA[t] = lofs;
    if (t >= 512 && t < 576) WlT[t-512] = ((t-512) < 56) ? ldf(W1, t-512, f32) : 0.f;
    if (t >= 576 && t < 584) adT[t-576] = ldf(ad1, t-576, f32);
    int incl1 = block_scan_incl(cnt, wpart);
    sc[t] = incl1;
    __syncthreads();
    int total = sc[1023];
    int ec    = min(total, BKCAP - nn);
    for (int pidx = t; pidx < ec; pidx += 1024){
        int lo = 0, hi = 511;
        while (lo < hi){ int mid = (lo + hi) >> 1; if (sc[mid] > pidx) hi = mid; else lo = mid + 1; }
        int segStart = lo ? sc[lo-1] : 0;
        pr[pidx] = stage[((size_t)lo << 14) + lofsA[lo] + (pidx - segStart)];
    }
    __syncthreads();
    for (int j = t; j < nn; j += 1024) pr[ec + j] = ((u32)(n0 + j) << 9) | (u32)j;  // self-loops
    int ecnt = ec + nn;
    for (int i = t; i < 4096; i += 1024) hist[i] = 0;
    __syncthreads();
    for (int i = t; i < ecnt; i += 1024){
        u32 pk = pr[i];
        int dl = pk & 511;
        int tile = min((int)(pk >> 9) >> 16, NTILE-1);
        atomicAdd(&hist[(tile << 9) + dl], 1);
    }
    __syncthreads();
    int base = t << 2, run = 0, loc[4];
    #pragma unroll
    for (int j = 0; j < 4; j++){ loc[j] = run; run += hist[base + j]; }
    int incl2 = block_scan_incl(run, wpart);
    int bex = incl2 - run;          // exclusive bin-group base
    __syncthreads();
    #pragma unroll
    for (int j = 0; j < 4; j++) hist[base + j] = bex + loc[j];
    // tile ti starts at bin ti*512 -> thread ti*128 (4 bins/thread), local bin 0
    if ((t & 127) == 0) tileOfs[(size_t)k*9 + (t >> 7)] = bex;
    if (t == 0)         tileOfs[(size_t)k*9 + 8] = ecnt;
    __syncthreads();
    size_t wbase = (size_t)k * BKCAP;
    for (int i = t; i < ecnt; i += 1024){
        u32 pk = pr[i];
        int dl = pk & 511;
        int tile = min((int)(pk >> 9) >> 16, NTILE-1);
        int p = atomicAdd(&hist[(tile << 9) + dl], 1);
        csr[wbase + p] = pk;
    }
    // ---- fused layer-1 transform for this block's node range ----
    if (t < nn){
        int i = n0 + t;
        float a[8];
        #pragma unroll
        for (int kk = 0; kk < 7; kk++) a[kk] = ldf(x, i*7 + kk, f32);
        a[7] = 0.f;
        float h[8];
        #pragma unroll
        for (int j = 0; j < 8; j++){
            float acc = 0.f;
            #pragma unroll
            for (int kk = 0; kk < 8; kk++) acc += a[kk]*WlT[kk*8+j];
            h[j] = acc;
        }
        float s2 = 0.f;
        #pragma unroll
        for (int j = 0; j < 8; j++) s2 += h[j]*adT[j];
        hd[i] = s2;
        hrec[i] = pack8(h);
    }
}

// ---------------- node transform (+ fused BN/PReLU of previous layer) ----------------
__global__ void k_transform(const uint4* __restrict__ actpk, const void* __restrict__ xraw,
                            const int* __restrict__ dflag, int fin,
                            const void* __restrict__ W, const void* __restrict__ adst,
                            const float* __restrict__ stats, const void* __restrict__ gamma,
                            const void* __restrict__ beta, const void* __restrict__ alpha,
                            uint4* __restrict__ hrec, float* __restrict__ hd, int n){
    const bool f32 = dflag[0] != 0;
    __shared__ float Wl[64], dl[8], scl[8], sft[8], alv;
    int t = threadIdx.x;
    if (t < 64)            Wl[t]   = (t < fin*8) ? ldf(W, t, f32) : 0.f;
    if (t >= 64 && t < 72) dl[t-64] = ldf(adst, t-64, f32);
    if (t == 80) alv = ldf(alpha, 0, f32);
    if (stats && t < 8){
        float invN = 1.f/(float)n;
        float mu  = stats[t]*invN;
        float var = fmaxf(stats[8+t]*invN - mu*mu, 0.f);
        float s   = ldf(gamma, t, f32)*rsqrtf(var + EPSBN);
        scl[t] = s; sft[t] = ldf(beta, t, f32) - mu*s;
    }
    __syncthreads();
    int i = blockIdx.x*blockDim.x + t;
    if (i >= n) return;
    float a[8];
    if (xraw){
        #pragma unroll
        for (int k=0;k<7;k++) a[k] = ldf(xraw, i*7 + k, f32);
        a[7] = 0.f;
    } else {
        unpack8(actpk[i], a);
        #pragma unroll
        for (int j=0;j<8;j++){
            float y = a[j]*scl[j] + sft[j];
            a[j] = (y > 0.f) ? y : alv*y;
        }
    }
    float h[8];
    #pragma unroll
    for (int j=0;j<8;j++){
        float acc = 0.f;
        #pragma unroll
        for (int k=0;k<8;k++) acc += a[k]*Wl[k*8+j];
        h[j] = acc;
    }
    float s2 = 0.f;
    #pragma unroll
    for (int j=0;j<8;j++) s2 += h[j]*dl[j];
    hd[i] = s2;
    hrec[i] = pack8(h);
}

// ---------------- GAT aggregate: tile-major, scalar-chain-in-A, zero-atomic ----------
__global__ __launch_bounds__(512) void k_aggregate(
        const u32* __restrict__ csr,
        const int* __restrict__ tileOfs,
        const uint4* __restrict__ hrec, const float* __restrict__ hd,
        const void* __restrict__ asrc, const int* __restrict__ dflag,
        uint4* __restrict__ act, float* __restrict__ stats, int n){
    const bool f32 = dflag[0] != 0;
    __shared__ u32   stg[4*SLOTS];   // 24KB: hv.x,y,z,w planes (bf16-packed)
    __shared__ float swp[SLOTS];     // 6KB: w plane
    __shared__ u16   sdl[SLOTS];     // 3KB: dl plane
    __shared__ float hdl[512];       // 2KB
    __shared__ u16 bs[512], be[512]; // 2KB run bounds per row
    __shared__ float alS[8];
    __shared__ float sred[8][16];
    __shared__ int tofS[9];
    int k = blockIdx.x, t = threadIdx.x;
    int n0 = k << 9;
    int nn = min(NPB, n - n0);
    if (t < 8) alS[t] = ldf(asrc, t, f32);
    if (t < 9) tofS[t] = tileOfs[(size_t)k*9 + t];
    hdl[t] = (t < nn) ? hd[n0 + t] : 0.f;
    const u32* ecsr = csr + (size_t)k * BKCAP;   // fixed-stride bucket base
    __syncthreads();
    float al[8];
    #pragma unroll
    for (int j = 0; j < 8; j++) al[j] = alS[j];
    float acc[8] = {0,0,0,0,0,0,0,0};
    float den = 0.f;

    // ---- flattened window walk: (wt, wc) -> first valid window ----
    int wt = 0, wc = 0;
    while (wt < NTILE && wc >= tofS[wt+1]){ wt++; if (wt < NTILE) wc = tofS[wt]; }

    u32 pkc[3]; uint4 hvc[3];
    if (wt < NTILE){
        int L = min(SLOTS, tofS[wt+1] - wc);
        #pragma unroll
        for (int j = 0; j < 3; j++) pkc[j] = ecsr[wc + min(t + (j << 9), L - 1)];
        #pragma unroll
        for (int j = 0; j < 3; j++) hvc[j] = hrec[pkc[j] >> 9];
    }

    while (wt < NTILE){
        int L = min(SLOTS, tofS[wt+1] - wc);
        __syncthreads();             // stg/swp/sdl/bs/be free (prev phase B done)
        // ---- phase A: stage hv + compute scalar chain (uniform) ----
        #pragma unroll
        for (int j = 0; j < 3; j++){
            int i = t + (j << 9);
            float h[8]; unpack8(hvc[j], h);
            int dl = (int)(pkc[j] & 511u);
            float e = hdl[dl];
            #pragma unroll
            for (int q = 0; q < 8; q++) e += h[q]*al[q];
            e = (e > 0.f) ? e : NEG_SLOPE*e;
            float w = __expf(e);
            if (i < L){
                stg[0*SLOTS + i] = hvc[j].x;
                stg[1*SLOTS + i] = hvc[j].y;
                stg[2*SLOTS + i] = hvc[j].z;
                stg[3*SLOTS + i] = hvc[j].w;
                swp[i] = w;
                sdl[i] = (u16)dl;
            }
        }
        bs[t] = 0; be[t] = 0;
        __syncthreads();             // stg + clears visible
        // ---- next window coords + register prefetch (hidden under detect+B) ----
        int nwt = wt, nwc = wc + SLOTS;
        while (nwt < NTILE && nwc >= tofS[nwt+1]){ nwt++; if (nwt < NTILE) nwc = tofS[nwt]; }
        if (nwt < NTILE){
            int Ln = min(SLOTS, tofS[nwt+1] - nwc);
            #pragma unroll
            for (int j = 0; j < 3; j++) pkc[j] = ecsr[nwc + min(t + (j << 9), Ln - 1)];
            #pragma unroll
            for (int j = 0; j < 3; j++) hvc[j] = hrec[pkc[j] >> 9];
        }
        // ---- boundary detect: dl sorted in window -> one run per row ----
        for (int i = t; i < L; i += 512){
            int dl = (int)sdl[i];
            if (i == 0){
                bs[dl] = 0;
            } else {
                int dp = (int)sdl[i - 1];
                if (dp != dl){ bs[dl] = (u16)i; be[dp] = (u16)i; }
            }
            if (i == L-1) be[dl] = (u16)L;
        }
        __syncthreads();             // bs/be ready
        // ---- phase B: row-owner weighted sum (unpack + FMA only) ----
        {
            int p0 = bs[t], p1 = be[t];
            for (int p = p0; p < p1; ++p){
                uint4 hv = make_uint4(stg[0*SLOTS + p], stg[1*SLOTS + p],
                                      stg[2*SLOTS + p], stg[3*SLOTS + p]);
                float h[8]; unpack8(hv, h);
                float w = swp[p];
                den += w;
                #pragma unroll
                for (int q = 0; q < 8; q++) acc[q] += w*h[q];
            }
        }
        wt = nwt; wc = nwc;
    }

    float o[8] = {0,0,0,0,0,0,0,0};
    if (t < nn){
        float inv = 1.f/(den + 1e-16f);
        #pragma unroll
        for (int j = 0; j < 8; j++) o[j] = acc[j]*inv;
        act[n0 + t] = pack8(o);
    }
    // BN stats partials (sum, sumsq per channel) -> global atomics
    float v[16];
    #pragma unroll
    for (int j=0;j<8;j++){ v[j]=o[j]; v[8+j]=o[j]*o[j]; }
    #pragma unroll
    for (int off=32; off>0; off>>=1){
        #pragma unroll
        for (int j=0;j<16;j++) v[j] += __shfl_down(v[j], off, 64);
    }
    int lane = t & 63, wv = t >> 6;
    if (lane == 0){
        #pragma unroll
        for (int j=0;j<16;j++) sred[wv][j] = v[j];
    }
    __syncthreads();
    if (t < 16){
        float tot = 0.f;
        #pragma unroll
        for (int w=0; w<8; w++) tot += sred[w][t];
        atomicAdd(&stats[t], tot);
    }
}

// ---------------- JK-cat (BN+PReLU fused) @ Wjk + bjk, pooled per graph ----------------
static __device__ __forceinline__ int lowerb(const int* __restrict__ a, int n, int key){
    int lo = 0, hi = n;
    while (lo < hi){ int mid = (lo + hi) >> 1; if (a[mid] < key) lo = mid + 1; else hi = mid; }
    return lo;
}

__global__ __launch_bounds__(256) void k_jkpool(
        const uint4* __restrict__ a1, const uint4* __restrict__ a2, const uint4* __restrict__ a3,
        const float* __restrict__ st1, const float* __restrict__ st2, const float* __restrict__ st3,
        const void* __restrict__ g1, const void* __restrict__ be1,
        const void* __restrict__ g2, const void* __restrict__ be2,
        const void* __restrict__ g3, const void* __restrict__ be3,
        const void* __restrict__ alpha,
        const void* __restrict__ Wjk, const void* __restrict__ bjk,
        const int* __restrict__ dflag,
        const int* __restrict__ batch, float* __restrict__ pooled, int n){
    const bool f32 = dflag[0] != 0;
    __shared__ float Wl[192], bl[8], scl[24], sft[24], alv;
    __shared__ int rng[2];
    int t = threadIdx.x, g = blockIdx.x;
    if (t < 192) Wl[t] = ldf(Wjk, t, f32);
    if (t < 8)   bl[t] = ldf(bjk, t, f32);
    if (t < 24){
        int L = t >> 3, j = t & 7;
        const float* st = (L==0)? st1 : (L==1)? st2 : st3;
        const void* gg  = (L==0)? g1  : (L==1)? g2  : g3;
        const void* bb_ = (L==0)? be1 : (L==1)? be2 : be3;
        float invN = 1.f/(float)n;
        float mu  = st[j]*invN;
        float var = fmaxf(st[8+j]*invN - mu*mu, 0.f);
        float s   = ldf(gg, j, f32)*rsqrtf(var + EPSBN);
        scl[t] = s; sft[t] = ldf(bb_, j, f32) - mu*s;
    }
    if (t == 30) alv = ldf(alpha, 0, f32);
    if (t == 0) rng[0] = lowerb(batch, n, g);
    if (t == 1) rng[1] = lowerb(batch, n, g+1);
    __syncthreads();
    int lo = rng[0], hi = rng[1];
    float pa[8] = {0,0,0,0,0,0,0,0};
    for (int i = lo + t; i < hi; i += 256){
        float c[24];
        unpack8(a1[i], c);
        unpack8(a2[i], c+8);
        unpack8(a3[i], c+16);
        #pragma unroll
        for (int k=0;k<24;k++){
            float y = c[k]*scl[k] + sft[k];
            c[k] = (y > 0.f) ? y : alv*y;
        }
        #pragma unroll
        for (int j=0;j<8;j++){
            float acc = bl[j];
            #pragma unroll
            for (int k=0;k<24;k++) acc += c[k]*Wl[k*8+j];
            pa[j] += acc;
        }
    }
    #pragma unroll
    for (int off=32; off>0; off>>=1){
        #pragma unroll
        for (int j=0;j<8;j++) pa[j] += __shfl_down(pa[j], off, 64);
    }
    __shared__ float sr[4][8];
    int lane = t & 63, wv = t >> 6;
    if (lane == 0){
        #pragma unroll
        for (int j=0;j<8;j++) sr[wv][j] = pa[j];
    }
    __syncthreads();
    if (t < 8){
        float tot = sr[0][t]+sr[1][t]+sr[2][t]+sr[3][t];
        pooled[(size_t)g*8 + t] = tot;
    }
}

// ---------------- MLP head ----------------
__global__ __launch_bounds__(1024) void k_final(
        const float* __restrict__ pooled,
        const void* __restrict__ Wm1, const void* __restrict__ bm1,
        const void* __restrict__ gm, const void* __restrict__ bem,
        const void* __restrict__ am,
        const void* __restrict__ Wm2, const void* __restrict__ bm2,
        const int* __restrict__ dflag,
        float* __restrict__ out, int G){
    const bool f32 = dflag[0] != 0;
    int t = threadIdx.x;
    float tv[8] = {0,0,0,0,0,0,0,0};
    if (t < G){
        float r[8];
        #pragma unroll
        for (int j=0;j<8;j++) r[j] = pooled[(size_t)t*8+j];
        #pragma unroll
        for (int j=0;j<8;j++){
            float acc = ldf(bm1, j, f32);
            #pragma unroll
            for (int k=0;k<8;k++) acc += r[k]*ldf(Wm1, k*8+j, f32);
            tv[j] = acc;
        }
    }
    float v[16];
    #pragma unroll
    for (int j=0;j<8;j++){ v[j]=tv[j]; v[8+j]=tv[j]*tv[j]; }
    #pragma unroll
    for (int off=32; off>0; off>>=1){
        #pragma unroll
        for (int j=0;j<16;j++) v[j] += __shfl_down(v[j], off, 64);
    }
    __shared__ float sred[16][16];
    int lane = t & 63, wv = t >> 6;
    if (lane == 0){
        #pragma unroll
        for (int j=0;j<16;j++) sred[wv][j] = v[j];
    }
    __syncthreads();
    __shared__ float stt[16];
    if (t < 16){
        float tot = 0.f;
        #pragma unroll
        for (int w=0; w<16; w++) tot += sred[w][t];
        stt[t] = tot;
    }
    __syncthreads();
    if (t < G){
        float a = ldf(am, 0, f32);
        float invG = 1.f/(float)G;
        float m1[8];
        #pragma unroll
        for (int j=0;j<8;j++){
            float mu  = stt[j]*invG;
            float var = fmaxf(stt[8+j]*invG - mu*mu, 0.f);
            float y = (tv[j]-mu)*rsqrtf(var+EPSBN)*ldf(gm,j,f32)+ldf(bem,j,f32);
            m1[j] = (y>0.f)? y : a*y;
        }
        #pragma unroll
        for (int c=0;c<2;c++){
            float oacc = ldf(bm2, c, f32);
            #pragma unroll
            for (int k=0;k<8;k++) oacc += m1[k]*ldf(Wm2, k*2+c, f32);
            out[(size_t)t*2+c] = oacc;
        }
    }
}

extern "C" void kernel_launch(void* const* d_in, const int* in_sizes, int n_in,
                              void* d_out, int out_size, void* d_ws, size_t ws_size,
                              hipStream_t stream){
    const u16* x16   = (const u16*)d_in[0];
    const void* x    = d_in[0];
    const int* ei    = (const int*)d_in[1];
    const int* batch = (const int*)d_in[2];
    int N = in_sizes[2];
    int E = in_sizes[1] / 2;
    const int* srcA = ei;
    const int* dstA = ei + E;
    const void *W1=d_in[3],  *as1=d_in[4],  *ad1=d_in[5];
    const void *W2=d_in[7],  *as2=d_in[8],  *ad2=d_in[9];
    const void *W3=d_in[11], *as3=d_in[12], *ad3=d_in[13];
    const void *g1=d_in[15], *be1=d_in[16];
    const void *g2=d_in[17], *be2=d_in[18];
    const void *g3=d_in[19], *be3=d_in[20];
    const void *agnn=d_in[21];
    const void *Wjk=d_in[22], *bjk=d_in[23];
    const void *Wm1=d_in[24], *bm1=d_in[25];
    const void *gm =d_in[26], *bem=d_in[27];
    const void *amlp=d_in[28];
    const void *Wm2=d_in[29], *bm2=d_in[30];

    char* p = (char*)d_ws;
    auto carve = [&](size_t bytes) -> void* {
        void* r = (void*)p;
        p += (bytes + 255) & ~(size_t)255;
        return r;
    };
    int nb512 = (N + 511)/512;
    int B  = (N + NPB - 1) / NPB;
    int NC = (E + CHUNK - 1) / CHUNK;          // <= 512
    int*   dflag  = (int*)  carve(256);
    int*   tileOfs= (int*)  carve((size_t)B*9*4);
    int*   matL   = (int*)  carve((size_t)NC*(B+1)*4);
    u32*   stage  = (u32*)  carve((size_t)NC*CHUNK*4);
    u32*   csr    = (u32*)  carve((size_t)B*BKCAP*4);   // fixed-stride buckets
    uint4* hrec   = (uint4*)carve((size_t)N*16);
    float* hd     = (float*)carve((size_t)N*4);
    uint4* act1   = (uint4*)carve((size_t)N*16);
    uint4* act2   = (uint4*)carve((size_t)N*16);
    uint4* act3   = (uint4*)carve((size_t)N*16);
    float* statsA = (float*)carve(256);        // 48 floats: stats1|stats2|stats3
    float* stats1 = statsA;
    float* stats2 = statsA + 16;
    float* stats3 = statsA + 32;
    float* pooled = (float*)carve((size_t)NGRAPH*32);
    (void)ws_size; (void)n_in;

    // ---- CSR build (+ sniff/stats init, + fused layer-1 transform) ----
    k_binsort <<<NC, 1024, 0, stream>>>(srcA, dstA, stage, matL, E, B, x16, dflag, statsA);
    k_bucket  <<<B, 1024, 0, stream>>>(stage, matL, tileOfs, csr, N, B, NC,
                                       x, W1, ad1, dflag, hrec, hd);

    // layer 1 aggregate (transform-1 already done in k_bucket)
    k_aggregate <<<B, 512, 0, stream>>>(csr, tileOfs, hrec, hd, as1, dflag, act1, stats1, N);
    // layer 2 (BN1+PReLU fused into transform)
    k_transform <<<nb512, 512, 0, stream>>>(act1, nullptr, dflag, 8, W2, ad2,
                                            stats1, g1, be1, agnn, hrec, hd, N);
    k_aggregate <<<B, 512, 0, stream>>>(csr, tileOfs, hrec, hd, as2, dflag, act2, stats2, N);
    // layer 3
    k_transform <<<nb512, 512, 0, stream>>>(act2, nullptr, dflag, 8, W3, ad3,
                                            stats2, g2, be2, agnn, hrec, hd, N);
    k_aggregate <<<B, 512, 0, stream>>>(csr, tileOfs, hrec, hd, as3, dflag, act3, stats3, N);

    // JK (BN+PReLU fused) + pool + head
    k_jkpool<<<NGRAPH, 256, 0, stream>>>(act1, act2, act3, stats1, stats2, stats3,
                                         g1, be1, g2, be2, g3, be3, agnn,
                                         Wjk, bjk, dflag, batch, pooled, N);
    int G = out_size / 2;
    k_final <<<1, 1024, 0, stream>>>(pooled, Wm1, bm1, gm, bem, amlp, Wm2, bm2, dflag, (float*)d_out, G);
}

// Round 15
// 508.367 us; speedup vs baseline: 1.1298x; 1.0046x over previous
//
#include <hip/hip_runtime.h>
#include <hip/hip_cooperative_groups.h>

namespace cg = cooperative_groups;

typedef unsigned short u16;
typedef unsigned int   u32;

#define EPSBN     1e-5f
#define NEG_SLOPE 0.2f
#define NGRAPH    1024
#define NPB       512         // nodes per bucket (dst >> 9)
#define CHUNK     16384       // edges per chunk (1 << 14); NC <= 512 assumed
#define BKCAP     11264       // LDS pair capacity per bucket == fixed csr stride
#define NTILE     8           // src tiles of 65536 nodes (1MB hrec, fits XCD L2)
#define SLOTS     1536        // staged edges per window (aggregate)

// LESSON (rounds 1-3): LDS f32 atomics ~200cy/wave-op, contention-independent.
// LESSON (round 4): tile coherence must be bucket-level -> sort by (tile, dl).
// LESSON (round 6): scatter live-region x concurrency must fit XCD L2.
// LESSON (round 8): bucket at per-edge-work floor (~60 Gkeys/s).
// LESSON (round 10/13): verify LDS AND VGPR occupancy arithmetic BEFORE fusing;
// never fuse register-heavy cold code into a hot path (jkpool 14->138us).
// ROUND 15: ~145us of wall time is inter-dispatch; fuse the 3-layer
// agg/transform pipeline into ONE cooperative kernel (grid.sync for stats +
// hrec; o[8] and hd live in registers across layers). launch_bounds(512,8)
// pins VGPR<=64 -> 4 blocks/CU x 256 = 1024 >= 977 co-resident (guaranteed).
// Occupancy-query + launch-error fallback to the round-14 path.

static __device__ __forceinline__ float bfl(const u16* __restrict__ p, int i){
    return __uint_as_float(((u32)p[i]) << 16);
}
static __device__ __forceinline__ float ldf(const void* __restrict__ p, int i, bool f32){
    return f32 ? ((const float*)p)[i] : bfl((const u16*)p, i);
}
static __device__ __forceinline__ u16 f2bf(float f){
    u32 u = __float_as_uint(f);
    return (u16)((u + 0x7fffu + ((u >> 16) & 1u)) >> 16);
}
static __device__ __forceinline__ void unpack8(uint4 pk, float* a){
    a[0] = __uint_as_float((pk.x & 0xffffu) << 16);
    a[1] = __uint_as_float( pk.x & 0xffff0000u);
    a[2] = __uint_as_float((pk.y & 0xffffu) << 16);
    a[3] = __uint_as_float( pk.y & 0xffff0000u);
    a[4] = __uint_as_float((pk.z & 0xffffu) << 16);
    a[5] = __uint_as_float( pk.z & 0xffff0000u);
    a[6] = __uint_as_float((pk.w & 0xffffu) << 16);
    a[7] = __uint_as_float( pk.w & 0xffff0000u);
}
static __device__ __forceinline__ uint4 pack8(const float* a){
    uint4 pk;
    pk.x = (u32)f2bf(a[0]) | ((u32)f2bf(a[1])<<16);
    pk.y = (u32)f2bf(a[2]) | ((u32)f2bf(a[3])<<16);
    pk.z = (u32)f2bf(a[4]) | ((u32)f2bf(a[5])<<16);
    pk.w = (u32)f2bf(a[6]) | ((u32)f2bf(a[7])<<16);
    return pk;
}

// ---------------- shuffle-based block scan (inclusive), <=16 waves ----------------
static __device__ __forceinline__ int wave_scan_incl(int x){
    int lane = threadIdx.x & 63;
    #pragma unroll
    for (int off = 1; off < 64; off <<= 1){
        int y = __shfl_up(x, off, 64);
        if (lane >= off) x += y;
    }
    return x;
}
static __device__ __forceinline__ int block_scan_incl(int x, int* wpart){
    int t = threadIdx.x, lane = t & 63, wv = t >> 6;
    int nw = blockDim.x >> 6;
    int ws = wave_scan_incl(x);
    __syncthreads();                 // protect wpart reuse across scans
    if (lane == 63) wpart[wv] = ws;
    __syncthreads();
    if (wv == 0){
        int p = (lane < nw) ? wpart[lane] : 0;
        p = wave_scan_incl(p);
        if (lane < nw) wpart[lane] = p;
    }
    __syncthreads();
    int base = wv ? wpart[wv-1] : 0;
    return base + ws;
}

// ================= atomic-free radix CSR build (LDS-staged chunk sort) =================
// Block 0 also: dtype sniff -> dflag[0], zero stats1/2/3.
__global__ __launch_bounds__(1024) void k_binsort(const int* __restrict__ src,
                                                  const int* __restrict__ dst,
                                                  u32* __restrict__ stage,
                                                  int* __restrict__ matL,
                                                  int E, int B,
                                                  const u16* __restrict__ x16,
                                                  int* __restrict__ dflag,
                                                  float* __restrict__ statsAll){
    __shared__ u32 pr[CHUNK];        // 64KB: sorted pairs
    __shared__ int h[2048];          // 8KB
    __shared__ int wpart[16];
    int c = blockIdx.x, t = threadIdx.x;
    if (c == 0){
        if (t < 64){
            bool hit = false;
            for (int i = t; i < 128; i += 64){
                float v = bfl(x16, i);
                if (!(fabsf(v) <= 1e6f)) hit = true;
            }
            unsigned long long m = __ballot(hit);
            if (t == 0) dflag[0] = (m != 0ull) ? 1 : 0;
        }
        if (t >= 64 && t < 112) statsAll[t - 64] = 0.f;
    }
    int e0 = c << 14, e1 = min(e0 + CHUNK, E), cn = e1 - e0;
    for (int b = t; b < B; b += 1024) h[b] = 0;
    __syncthreads();
    for (int i = e0 + t; i < e1; i += 1024) atomicAdd(&h[dst[i] >> 9], 1);
    __syncthreads();
    int base = t << 1, run = 0, loc[2];     // per = 2 (B <= 2048)
    #pragma unroll
    for (int j = 0; j < 2; j++){
        int b = base + j;
        int v = (b < B) ? h[b] : 0;
        loc[j] = run; run += v;
    }
    int incl = block_scan_incl(run, wpart);
    int bex = incl - run;
    __syncthreads();
    #pragma unroll
    for (int j = 0; j < 2; j++){
        int b = base + j;
        if (b < B) h[b] = bex + loc[j];
    }
    __syncthreads();
    int* mrow = matL + (size_t)c * (B+1);
    for (int b = t; b < B; b += 1024) mrow[b] = h[b];
    if (t == 0) mrow[B] = cn;
    __syncthreads();
    for (int i = e0 + t; i < e1; i += 1024){
        int d = dst[i];
        int b = d >> 9;
        int p = atomicAdd(&h[b], 1);
        pr[p] = ((u32)src[i] << 9) | (u32)(d & 511);
    }
    __syncthreads();
    u32* srow = stage + ((size_t)c << 14);
    for (int i = t; i < cn; i += 1024) srow[i] = pr[i];
}

// per-bucket single-pass counting sort by (srcTile<<9)|dl, LDS-staged pr.
// + fused layer-1 transform for its node range.
__global__ __launch_bounds__(1024) void k_bucket(const u32* __restrict__ stage,
                                                 const int* __restrict__ matL,
                                                 int* __restrict__ tileOfs,
                                                 u32* __restrict__ csr,
                                                 int N, int B, int NC,
                                                 const void* __restrict__ x,
                                                 const void* __restrict__ W1,
                                                 const void* __restrict__ ad1,
                                                 const int* __restrict__ dflag,
                                                 uint4* __restrict__ hrec,
                                                 float* __restrict__ hd){
    __shared__ u32 pr[BKCAP];        // 44KB
    __shared__ int hist[4096];       // 16KB: (tile<<9)|dl
    __shared__ int sc[1024];         // 4KB: searchable chunk-prefix
    __shared__ int lofsA[512];       // 2KB
    __shared__ int wpart[16];
    __shared__ float WlT[64], adT[8];
    int k = blockIdx.x, t = threadIdx.x;
    int n0 = k << 9, n1 = min(n0 + NPB, N), nn = n1 - n0;
    const bool f32 = dflag[0] != 0;
    int cnt = 0, lofs = 0;
    if (t < NC){
        lofs = matL[(size_t)t*(B+1) + k];
        cnt  = matL[(size_t)t*(B+1) + k + 1] - lofs;
    }
    if (t < 512) lofsA[t] = lofs;
    if (t >= 512 && t < 576) WlT[t-512] = ((t-512) < 56) ? ldf(W1, t-512, f32) : 0.f;
    if (t >= 576 && t < 584) adT[t-576] = ldf(ad1, t-576, f32);
    int incl1 = block_scan_incl(cnt, wpart);
    sc[t] = incl1;
    __syncthreads();
    int total = sc[1023];
    int ec    = min(total, BKCAP - nn);
    for (int pidx = t; pidx < ec; pidx += 1024){
        int lo = 0, hi = 511;
        while (lo < hi){ int mid = (lo + hi) >> 1; if (sc[mid] > pidx) hi = mid; else lo = mid + 1; }
        int segStart = lo ? sc[lo-1] : 0;
        pr[pidx] = stage[((size_t)lo << 14) + lofsA[lo] + (pidx - segStart)];
    }
    __syncthreads();
    for (int j = t; j < nn; j += 1024) pr[ec + j] = ((u32)(n0 + j) << 9) | (u32)j;  // self-loops
    int ecnt = ec + nn;
    for (int i = t; i < 4096; i += 1024) hist[i] = 0;
    __syncthreads();
    for (int i = t; i < ecnt; i += 1024){
        u32 pk = pr[i];
        int dl = pk & 511;
        int tile = min((int)(pk >> 9) >> 16, NTILE-1);
        atomicAdd(&hist[(tile << 9) + dl], 1);
    }
    __syncthreads();
    int base = t << 2, run = 0, loc[4];
    #pragma unroll
    for (int j = 0; j < 4; j++){ loc[j] = run; run += hist[base + j]; }
    int incl2 = block_scan_incl(run, wpart);
    int bex = incl2 - run;          // exclusive bin-group base
    __syncthreads();
    #pragma unroll
    for (int j = 0; j < 4; j++) hist[base + j] = bex + loc[j];
    if ((t & 127) == 0) tileOfs[(size_t)k*9 + (t >> 7)] = bex;
    if (t == 0)         tileOfs[(size_t)k*9 + 8] = ecnt;
    __syncthreads();
    size_t wbase = (size_t)k * BKCAP;
    for (int i = t; i < ecnt; i += 1024){
        u32 pk = pr[i];
        int dl = pk & 511;
        int tile = min((int)(pk >> 9) >> 16, NTILE-1);
        int p = atomicAdd(&hist[(tile << 9) + dl], 1);
        csr[wbase + p] = pk;
    }
    // ---- fused layer-1 transform for this block's node range ----
    if (t < nn){
        int i = n0 + t;
        float a[8];
        #pragma unroll
        for (int kk = 0; kk < 7; kk++) a[kk] = ldf(x, i*7 + kk, f32);
        a[7] = 0.f;
        float h[8];
        #pragma unroll
        for (int j = 0; j < 8; j++){
            float acc = 0.f;
            #pragma unroll
            for (int kk = 0; kk < 8; kk++) acc += a[kk]*WlT[kk*8+j];
            h[j] = acc;
        }
        float s2 = 0.f;
        #pragma unroll
        for (int j = 0; j < 8; j++) s2 += h[j]*adT[j];
        hd[i] = s2;
        hrec[i] = pack8(h);
    }
}

// ---------------- shared aggregate body (tile-major, scalar-chain-in-A) ----------
static __device__ __forceinline__ void agg_body(
        const u32* __restrict__ ecsr, const int* __restrict__ tof,
        const uint4* __restrict__ hrec,
        const void* __restrict__ asrc, bool f32, float hdv,
        int nn, int n0, int t,
        uint4* __restrict__ act, float* __restrict__ stats,
        u32* stg, float* swp, u16* sdl, float* hdl,
        u16* bs, u16* be, float* alS, float* sred, int* tofS,
        float* o)
{
    if (t < 8) alS[t] = ldf(asrc, t, f32);
    if (t < 9) tofS[t] = tof[t];
    hdl[t] = (t < nn) ? hdv : 0.f;
    __syncthreads();
    float al[8];
    #pragma unroll
    for (int j = 0; j < 8; j++) al[j] = alS[j];
    float acc[8] = {0,0,0,0,0,0,0,0};
    float den = 0.f;

    int wt = 0, wc = 0;
    while (wt < NTILE && wc >= tofS[wt+1]){ wt++; if (wt < NTILE) wc = tofS[wt]; }
    u32 pkc[3]; uint4 hvc[3];
    if (wt < NTILE){
        int L = min(SLOTS, tofS[wt+1] - wc);
        #pragma unroll
        for (int j = 0; j < 3; j++) pkc[j] = ecsr[wc + min(t + (j << 9), L - 1)];
        #pragma unroll
        for (int j = 0; j < 3; j++) hvc[j] = hrec[pkc[j] >> 9];
    }
    while (wt < NTILE){
        int L = min(SLOTS, tofS[wt+1] - wc);
        __syncthreads();             // stg/swp/sdl/bs/be free
        #pragma unroll
        for (int j = 0; j < 3; j++){
            int i = t + (j << 9);
            float h[8]; unpack8(hvc[j], h);
            int dl = (int)(pkc[j] & 511u);
            float e = hdl[dl];
            #pragma unroll
            for (int q = 0; q < 8; q++) e += h[q]*al[q];
            e = (e > 0.f) ? e : NEG_SLOPE*e;
            float w = __expf(e);
            if (i < L){
                stg[0*SLOTS + i] = hvc[j].x;
                stg[1*SLOTS + i] = hvc[j].y;
                stg[2*SLOTS + i] = hvc[j].z;
                stg[3*SLOTS + i] = hvc[j].w;
                swp[i] = w;
                sdl[i] = (u16)dl;
            }
        }
        bs[t] = 0; be[t] = 0;
        __syncthreads();
        int nwt = wt, nwc = wc + SLOTS;
        while (nwt < NTILE && nwc >= tofS[nwt+1]){ nwt++; if (nwt < NTILE) nwc = tofS[nwt]; }
        if (nwt < NTILE){
            int Ln = min(SLOTS, tofS[nwt+1] - nwc);
            #pragma unroll
            for (int j = 0; j < 3; j++) pkc[j] = ecsr[nwc + min(t + (j << 9), Ln - 1)];
            #pragma unroll
            for (int j = 0; j < 3; j++) hvc[j] = hrec[pkc[j] >> 9];
        }
        for (int i = t; i < L; i += 512){
            int dl = (int)sdl[i];
            if (i == 0){
                bs[dl] = 0;
            } else {
                int dp = (int)sdl[i - 1];
                if (dp != dl){ bs[dl] = (u16)i; be[dp] = (u16)i; }
            }
            if (i == L-1) be[dl] = (u16)L;
        }
        __syncthreads();
        {
            int p0 = bs[t], p1 = be[t];
            for (int p = p0; p < p1; ++p){
                uint4 hv = make_uint4(stg[0*SLOTS + p], stg[1*SLOTS + p],
                                      stg[2*SLOTS + p], stg[3*SLOTS + p]);
                float h[8]; unpack8(hv, h);
                float w = swp[p];
                den += w;
                #pragma unroll
                for (int q = 0; q < 8; q++) acc[q] += w*h[q];
            }
        }
        wt = nwt; wc = nwc;
    }

    #pragma unroll
    for (int j = 0; j < 8; j++) o[j] = 0.f;
    if (t < nn){
        float inv = 1.f/(den + 1e-16f);
        #pragma unroll
        for (int j = 0; j < 8; j++) o[j] = acc[j]*inv;
        act[n0 + t] = pack8(o);
    }
    float v[16];
    #pragma unroll
    for (int j=0;j<8;j++){ v[j]=o[j]; v[8+j]=o[j]*o[j]; }
    #pragma unroll
    for (int off=32; off>0; off>>=1){
        #pragma unroll
        for (int j=0;j<16;j++) v[j] += __shfl_down(v[j], off, 64);
    }
    int lane = t & 63, wv = t >> 6;
    if (lane == 0){
        #pragma unroll
        for (int j=0;j<16;j++) sred[wv*16+j] = v[j];
    }
    __syncthreads();
    if (t < 16){
        float tot = 0.f;
        #pragma unroll
        for (int w=0; w<8; w++) tot += sred[w*16+t];
        atomicAdd(&stats[t], tot);
    }
}

// ---------------- shared transform body (BN+PReLU + 8x8 matmul), block-local -------
static __device__ __forceinline__ float tr_body(
        const float* __restrict__ o,
        const float* __restrict__ stats,
        const void* __restrict__ gamma, const void* __restrict__ beta,
        const void* __restrict__ alpha,
        const void* __restrict__ W, const void* __restrict__ adst,
        bool f32, int nn, int t, int i, int n,
        uint4* __restrict__ hrec, float* __restrict__ trS)
{
    if (t < 64)            trS[t] = ldf(W, t, f32);
    else if (t < 72)       trS[t] = ldf(adst, t-64, f32);
    else if (t < 80){
        int j = t - 72;
        float invN = 1.f/(float)n;
        float mu  = stats[j]*invN;
        float var = fmaxf(stats[8+j]*invN - mu*mu, 0.f);
        trS[t] = ldf(gamma, j, f32)*rsqrtf(var + EPSBN);        // scl
    } else if (t < 88){
        int j = t - 80;
        float invN = 1.f/(float)n;
        float mu  = stats[j]*invN;
        float var = fmaxf(stats[8+j]*invN - mu*mu, 0.f);
        float s   = ldf(gamma, j, f32)*rsqrtf(var + EPSBN);
        trS[t] = ldf(beta, j, f32) - mu*s;                      // sft
    } else if (t == 88)    trS[88] = ldf(alpha, 0, f32);
    __syncthreads();
    float hdv = 0.f;
    if (t < nn){
        float a[8];
        #pragma unroll
        for (int j = 0; j < 8; j++){
            float y = o[j]*trS[72+j] + trS[80+j];
            a[j] = (y > 0.f) ? y : trS[88]*y;
        }
        float h[8];
        #pragma unroll
        for (int j = 0; j < 8; j++){
            float s = 0.f;
            #pragma unroll
            for (int kk = 0; kk < 8; kk++) s += a[kk]*trS[kk*8+j];
            h[j] = s;
        }
        #pragma unroll
        for (int j = 0; j < 8; j++) hdv += h[j]*trS[64+j];
        hrec[i] = pack8(h);
    }
    return hdv;
}

// ---------------- cooperative 3-layer pipeline ----------------
__global__ __launch_bounds__(512, 8) void k_layers(
        const u32* __restrict__ csr, const int* __restrict__ tileOfs,
        uint4* __restrict__ hrec, const float* __restrict__ hd,
        const void* __restrict__ as1, const void* __restrict__ as2,
        const void* __restrict__ as3,
        const void* __restrict__ W2, const void* __restrict__ ad2,
        const void* __restrict__ W3, const void* __restrict__ ad3,
        const void* __restrict__ g1, const void* __restrict__ be1,
        const void* __restrict__ g2, const void* __restrict__ be2,
        const void* __restrict__ agnn, const int* __restrict__ dflag,
        uint4* __restrict__ act1, uint4* __restrict__ act2,
        uint4* __restrict__ act3,
        float* __restrict__ statsA, int N)
{
    __shared__ u32   stg[4*SLOTS];   // 24KB
    __shared__ float swp[SLOTS];     // 6KB
    __shared__ u16   sdl[SLOTS];     // 3KB
    __shared__ float hdl[512];       // 2KB
    __shared__ u16 bsA[512], beA[512];
    __shared__ float alS[8];
    __shared__ float sred[128];
    __shared__ int tofS[9];
    __shared__ float trS[96];
    cg::grid_group grid = cg::this_grid();
    int k = blockIdx.x, t = threadIdx.x;
    int n0 = k << 9;
    int nn = min(NPB, N - n0);
    bool f32 = dflag[0] != 0;
    const u32* ecsr = csr + (size_t)k * BKCAP;
    const int* tof  = tileOfs + (size_t)k * 9;
    float* s1 = statsA, *s2 = statsA + 16, *s3 = statsA + 32;
    float hdv = (t < nn) ? hd[n0 + t] : 0.f;
    float o[8];

    agg_body(ecsr, tof, hrec, as1, f32, hdv, nn, n0, t, act1, s1,
             stg, swp, sdl, hdl, bsA, beA, alS, sred, tofS, o);
    __threadfence(); grid.sync(); __threadfence();
    hdv = tr_body(o, s1, g1, be1, agnn, W2, ad2, f32, nn, t, n0 + t, N, hrec, trS);
    __threadfence(); grid.sync(); __threadfence();
    agg_body(ecsr, tof, hrec, as2, f32, hdv, nn, n0, t, act2, s2,
             stg, swp, sdl, hdl, bsA, beA, alS, sred, tofS, o);
    __threadfence(); grid.sync(); __threadfence();
    hdv = tr_body(o, s2, g2, be2, agnn, W3, ad3, f32, nn, t, n0 + t, N, hrec, trS);
    __threadfence(); grid.sync(); __threadfence();
    agg_body(ecsr, tof, hrec, as3, f32, hdv, nn, n0, t, act3, s3,
             stg, swp, sdl, hdl, bsA, beA, alS, sred, tofS, o);
}

// ---------------- standalone fallback kernels (round-14 path) ----------------
__global__ void k_transform(const uint4* __restrict__ actpk, const void* __restrict__ xraw,
                            const int* __restrict__ dflag, int fin,
                            const void* __restrict__ W, const void* __restrict__ adst,
                            const float* __restrict__ stats, const void* __restrict__ gamma,
                            const void* __restrict__ beta, const void* __restrict__ alpha,
                            uint4* __restrict__ hrec, float* __restrict__ hd, int n){
    const bool f32 = dflag[0] != 0;
    __shared__ float Wl[64], dl[8], scl[8], sft[8], alv;
    int t = threadIdx.x;
    if (t < 64)            Wl[t]   = (t < fin*8) ? ldf(W, t, f32) : 0.f;
    if (t >= 64 && t < 72) dl[t-64] = ldf(adst, t-64, f32);
    if (t == 80) alv = ldf(alpha, 0, f32);
    if (stats && t < 8){
        float invN = 1.f/(float)n;
        float mu  = stats[t]*invN;
        float var = fmaxf(stats[8+t]*invN - mu*mu, 0.f);
        float s   = ldf(gamma, t, f32)*rsqrtf(var + EPSBN);
        scl[t] = s; sft[t] = ldf(beta, t, f32) - mu*s;
    }
    __syncthreads();
    int i = blockIdx.x*blockDim.x + t;
    if (i >= n) return;
    float a[8];
    if (xraw){
        #pragma unroll
        for (int k=0;k<7;k++) a[k] = ldf(xraw, i*7 + k, f32);
        a[7] = 0.f;
    } else {
        unpack8(actpk[i], a);
        #pragma unroll
        for (int j=0;j<8;j++){
            float y = a[j]*scl[j] + sft[j];
            a[j] = (y > 0.f) ? y : alv*y;
        }
    }
    float h[8];
    #pragma unroll
    for (int j=0;j<8;j++){
        float acc = 0.f;
        #pragma unroll
        for (int k=0;k<8;k++) acc += a[k]*Wl[k*8+j];
        h[j] = acc;
    }
    float s2 = 0.f;
    #pragma unroll
    for (int j=0;j<8;j++) s2 += h[j]*dl[j];
    hd[i] = s2;
    hrec[i] = pack8(h);
}

__global__ __launch_bounds__(512) void k_aggregate(
        const u32* __restrict__ csr,
        const int* __restrict__ tileOfs,
        const uint4* __restrict__ hrec, const float* __restrict__ hd,
        const void* __restrict__ asrc, const int* __restrict__ dflag,
        uint4* __restrict__ act, float* __restrict__ stats, int n){
    __shared__ u32   stg[4*SLOTS];
    __shared__ float swp[SLOTS];
    __shared__ u16   sdl[SLOTS];
    __shared__ float hdl[512];
    __shared__ u16 bsA[512], beA[512];
    __shared__ float alS[8];
    __shared__ float sred[128];
    __shared__ int tofS[9];
    int k = blockIdx.x, t = threadIdx.x;
    int n0 = k << 9;
    int nn = min(NPB, n - n0);
    bool f32 = dflag[0] != 0;
    float hdv = (t < nn) ? hd[n0 + t] : 0.f;
    float o[8];
    agg_body(csr + (size_t)k*BKCAP, tileOfs + (size_t)k*9, hrec, asrc, f32, hdv,
             nn, n0, t, act, stats, stg, swp, sdl, hdl, bsA, beA, alS, sred, tofS, o);
}

// ---------------- JK-cat (BN+PReLU fused) @ Wjk + bjk, pooled per graph ----------------
static __device__ __forceinline__ int lowerb(const int* __restrict__ a, int n, int key){
    int lo = 0, hi = n;
    while (lo < hi){ int mid = (lo + hi) >> 1; if (a[mid] < key) lo = mid + 1; else hi = mid; }
    return lo;
}

__global__ __launch_bounds__(256) void k_jkpool(
        const uint4* __restrict__ a1, const uint4* __restrict__ a2, const uint4* __restrict__ a3,
        const float* __restrict__ st1, const float* __restrict__ st2, const float* __restrict__ st3,
        const void* __restrict__ g1, const void* __restrict__ be1,
        const void* __restrict__ g2, const void* __restrict__ be2,
        const void* __restrict__ g3, const void* __restrict__ be3,
        const void* __restrict__ alpha,
        const void* __restrict__ Wjk, const void* __restrict__ bjk,
        const int* __restrict__ dflag,
        const int* __restrict__ batch, float* __restrict__ pooled, int n){
    const bool f32 = dflag[0] != 0;
    __shared__ float Wl[192], bl[8], scl[24], sft[24], alv;
    __shared__ int rng[2];
    int t = threadIdx.x, g = blockIdx.x;
    if (t < 192) Wl[t] = ldf(Wjk, t, f32);
    if (t < 8)   bl[t] = ldf(bjk, t, f32);
    if (t < 24){
        int L = t >> 3, j = t & 7;
        const float* st = (L==0)? st1 : (L==1)? st2 : st3;
        const void* gg  = (L==0)? g1  : (L==1)? g2  : g3;
        const void* bb_ = (L==0)? be1 : (L==1)? be2 : be3;
        float invN = 1.f/(float)n;
        float mu  = st[j]*invN;
        float var = fmaxf(st[8+j]*invN - mu*mu, 0.f);
        float s   = ldf(gg, j, f32)*rsqrtf(var + EPSBN);
        scl[t] = s; sft[t] = ldf(bb_, j, f32) - mu*s;
    }
    if (t == 30) alv = ldf(alpha, 0, f32);
    if (t == 0) rng[0] = lowerb(batch, n, g);
    if (t == 1) rng[1] = lowerb(batch, n, g+1);
    __syncthreads();
    int lo = rng[0], hi = rng[1];
    float pa[8] = {0,0,0,0,0,0,0,0};
    for (int i = lo + t; i < hi; i += 256){
        float c[24];
        unpack8(a1[i], c);
        unpack8(a2[i], c+8);
        unpack8(a3[i], c+16);
        #pragma unroll
        for (int k=0;k<24;k++){
            float y = c[k]*scl[k] + sft[k];
            c[k] = (y > 0.f) ? y : alv*y;
        }
        #pragma unroll
        for (int j=0;j<8;j++){
            float acc = bl[j];
            #pragma unroll
            for (int k=0;k<24;k++) acc += c[k]*Wl[k*8+j];
            pa[j] += acc;
        }
    }
    #pragma unroll
    for (int off=32; off>0; off>>=1){
        #pragma unroll
        for (int j=0;j<8;j++) pa[j] += __shfl_down(pa[j], off, 64);
    }
    __shared__ float sr[4][8];
    int lane = t & 63, wv = t >> 6;
    if (lane == 0){
        #pragma unroll
        for (int j=0;j<8;j++) sr[wv][j] = pa[j];
    }
    __syncthreads();
    if (t < 8){
        float tot = sr[0][t]+sr[1][t]+sr[2][t]+sr[3][t];
        pooled[(size_t)g*8 + t] = tot;
    }
}

// ---------------- MLP head ----------------
__global__ __launch_bounds__(1024) void k_final(
        const float* __restrict__ pooled,
        const void* __restrict__ Wm1, const void* __restrict__ bm1,
        const void* __restrict__ gm, const void* __restrict__ bem,
        const void* __restrict__ am,
        const void* __restrict__ Wm2, const void* __restrict__ bm2,
        const int* __restrict__ dflag,
        float* __restrict__ out, int G){
    const bool f32 = dflag[0] != 0;
    int t = threadIdx.x;
    float tv[8] = {0,0,0,0,0,0,0,0};
    if (t < G){
        float r[8];
        #pragma unroll
        for (int j=0;j<8;j++) r[j] = pooled[(size_t)t*8+j];
        #pragma unroll
        for (int j=0;j<8;j++){
            float acc = ldf(bm1, j, f32);
            #pragma unroll
            for (int k=0;k<8;k++) acc += r[k]*ldf(Wm1, k*8+j, f32);
            tv[j] = acc;
        }
    }
    float v[16];
    #pragma unroll
    for (int j=0;j<8;j++){ v[j]=tv[j]; v[8+j]=tv[j]*tv[j]; }
    #pragma unroll
    for (int off=32; off>0; off>>=1){
        #pragma unroll
        for (int j=0;j<16;j++) v[j] += __shfl_down(v[j], off, 64);
    }
    __shared__ float sred[16][16];
    int lane = t & 63, wv = t >> 6;
    if (lane == 0){
        #pragma unroll
        for (int j=0;j<16;j++) sred[wv][j] = v[j];
    }
    __syncthreads();
    __shared__ float stt[16];
    if (t < 16){
        float tot = 0.f;
        #pragma unroll
        for (int w=0; w<16; w++) tot += sred[w][t];
        stt[t] = tot;
    }
    __syncthreads();
    if (t < G){
        float a = ldf(am, 0, f32);
        float invG = 1.f/(float)G;
        float m1[8];
        #pragma unroll
        for (int j=0;j<8;j++){
            float mu  = stt[j]*invG;
            float var = fmaxf(stt[8+j]*invG - mu*mu, 0.f);
            float y = (tv[j]-mu)*rsqrtf(var+EPSBN)*ldf(gm,j,f32)+ldf(bem,j,f32);
            m1[j] = (y>0.f)? y : a*y;
        }
        #pragma unroll
        for (int c=0;c<2;c++){
            float oacc = ldf(bm2, c, f32);
            #pragma unroll
            for (int k=0;k<8;k++) oacc += m1[k]*ldf(Wm2, k*2+c, f32);
            out[(size_t)t*2+c] = oacc;
        }
    }
}

extern "C" void kernel_launch(void* const* d_in, const int* in_sizes, int n_in,
                              void* d_out, int out_size, void* d_ws, size_t ws_size,
                              hipStream_t stream){
    const u16* x16   = (const u16*)d_in[0];
    const void* x    = d_in[0];
    const int* ei    = (const int*)d_in[1];
    const int* batch = (const int*)d_in[2];
    int N = in_sizes[2];
    int E = in_sizes[1] / 2;
    const int* srcA = ei;
    const int* dstA = ei + E;
    const void *W1=d_in[3],  *as1=d_in[4],  *ad1=d_in[5];
    const void *W2=d_in[7],  *as2=d_in[8],  *ad2=d_in[9];
    const void *W3=d_in[11], *as3=d_in[12], *ad3=d_in[13];
    const void *g1=d_in[15], *be1=d_in[16];
    const void *g2=d_in[17], *be2=d_in[18];
    const void *g3=d_in[19], *be3=d_in[20];
    const void *agnn=d_in[21];
    const void *Wjk=d_in[22], *bjk=d_in[23];
    const void *Wm1=d_in[24], *bm1=d_in[25];
    const void *gm =d_in[26], *bem=d_in[27];
    const void *amlp=d_in[28];
    const void *Wm2=d_in[29], *bm2=d_in[30];

    char* p = (char*)d_ws;
    auto carve = [&](size_t bytes) -> void* {
        void* r = (void*)p;
        p += (bytes + 255) & ~(size_t)255;
        return r;
    };
    int nb512 = (N + 511)/512;
    int B  = (N + NPB - 1) / NPB;
    int NC = (E + CHUNK - 1) / CHUNK;          // <= 512
    int*   dflag  = (int*)  carve(256);
    int*   tileOfs= (int*)  carve((size_t)B*9*4);
    int*   matL   = (int*)  carve((size_t)NC*(B+1)*4);
    u32*   stage  = (u32*)  carve((size_t)NC*CHUNK*4);
    u32*   csr    = (u32*)  carve((size_t)B*BKCAP*4);   // fixed-stride buckets
    uint4* hrec   = (uint4*)carve((size_t)N*16);
    float* hd     = (float*)carve((size_t)N*4);
    uint4* act1   = (uint4*)carve((size_t)N*16);
    uint4* act2   = (uint4*)carve((size_t)N*16);
    uint4* act3   = (uint4*)carve((size_t)N*16);
    float* statsA = (float*)carve(256);        // 48 floats: stats1|stats2|stats3
    float* stats1 = statsA;
    float* stats2 = statsA + 16;
    float* stats3 = statsA + 32;
    float* pooled = (float*)carve((size_t)NGRAPH*32);
    (void)ws_size; (void)n_in;

    // ---- CSR build (+ sniff/stats init, + fused layer-1 transform) ----
    k_binsort <<<NC, 1024, 0, stream>>>(srcA, dstA, stage, matL, E, B, x16, dflag, statsA);
    k_bucket  <<<B, 1024, 0, stream>>>(stage, matL, tileOfs, csr, N, B, NC,
                                       x, W1, ad1, dflag, hrec, hd);

    // ---- cooperative 3-layer pipeline (fallback: separate kernels) ----
    bool coopDone = false;
    {
        static int cap = -1;
        if (cap < 0){
            int nbk = 0, dev = 0, ncu = 0;
            if (hipGetDevice(&dev) == hipSuccess){
                hipDeviceProp_t prop;
                if (hipGetDeviceProperties(&prop, dev) == hipSuccess) ncu = prop.multiProcessorCount;
            }
            if (ncu > 0 &&
                hipOccupancyMaxActiveBlocksPerMultiprocessor(&nbk, k_layers, 512, 0) == hipSuccess)
                cap = nbk * ncu;
            else
                cap = 0;
        }
        if (cap >= B){
            uint4* hrecA = hrec;
            int Nv = N;
            void* kargs[22] = {
                (void*)&csr, (void*)&tileOfs, (void*)&hrecA, (void*)&hd,
                (void*)&as1, (void*)&as2, (void*)&as3,
                (void*)&W2, (void*)&ad2, (void*)&W3, (void*)&ad3,
                (void*)&g1, (void*)&be1, (void*)&g2, (void*)&be2,
                (void*)&agnn, (void*)&dflag,
                (void*)&act1, (void*)&act2, (void*)&act3,
                (void*)&statsA, (void*)&Nv
            };
            hipError_t ce = hipLaunchCooperativeKernel((void*)k_layers, dim3(B), dim3(512),
                                                       kargs, 0, stream);
            coopDone = (ce == hipSuccess);
        }
    }
    if (!coopDone){
        k_aggregate <<<B, 512, 0, stream>>>(csr, tileOfs, hrec, hd, as1, dflag, act1, stats1, N);
        k_transform <<<nb512, 512, 0, stream>>>(act1, nullptr, dflag, 8, W2, ad2,
                                                stats1, g1, be1, agnn, hrec, hd, N);
        k_aggregate <<<B, 512, 0, stream>>>(csr, tileOfs, hrec, hd, as2, dflag, act2, stats2, N);
        k_transform <<<nb512, 512, 0, stream>>>(act2, nullptr, dflag, 8, W3, ad3,
                                                stats2, g2, be2, agnn, hrec, hd, N);
        k_aggregate <<<B, 512, 0, stream>>>(csr, tileOfs, hrec, hd, as3, dflag, act3, stats3, N);
    }

    // JK (BN+PReLU fused) + pool + head
    k_jkpool<<<NGRAPH, 256, 0, stream>>>(act1, act2, act3, stats1, stats2, stats3,
                                         g1, be1, g2, be2, g3, be3, agnn,
                                         Wjk, bjk, dflag, batch, pooled, N);
    int G = out_size / 2;
    k_final <<<1, 1024, 0, stream>>>(pooled, Wm1, bm1, gm, bem, amlp, Wm2, bm2, dflag, (float*)d_out, G);
}